// Round 5
// baseline (18947.916 us; speedup 1.0000x reference)
//
#include <hip/hip_runtime.h>
#include <hip/hip_cooperative_groups.h>
#include <stdint.h>

namespace cg = cooperative_groups;

#define E_DIM 2048
#define H_DIM 2048
#define B_DIM 512
#define T_DIM 256
#define G4H   8192  // 4*H

typedef unsigned short u16;
typedef __attribute__((ext_vector_type(8))) short bf16x8;
typedef __attribute__((ext_vector_type(8))) unsigned short u16x8;
typedef __attribute__((ext_vector_type(4))) float f32x4;

__device__ inline u16 f2b(float f) {
  union { float f; uint32_t i; } v; v.f = f;
  uint32_t u = v.i;
  return (u16)((u + 0x7FFFu + ((u >> 16) & 1u)) >> 16);  // RNE
}
__device__ inline float b2f(u16 u) {
  union { uint32_t i; float f; } v; v.i = ((uint32_t)u) << 16; return v.f;
}

__global__ __launch_bounds__(256) void convert_bf16(const float* __restrict__ s,
                                                    u16* __restrict__ d, int n4) {
  int i = blockIdx.x * 256 + threadIdx.x;
  if (i < n4) {
    float4 f = ((const float4*)s)[i];
    ushort4 o;
    o.x = f2b(f.x); o.y = f2b(f.y); o.z = f2b(f.z); o.w = f2b(f.w);
    ((ushort4*)d)[i] = o;
  }
}

// W_eff = W_hh + W_ih @ W_out (rank-2 fold), in MFMA-B-fragment order.
// Chunk id = (n16*64 + k32)*64 + lane holds 8 bf16 of
//   B[n' = n16*16 + (lane&15)][k = k32*32 + (lane>>4)*8 + j]
// n' gate-interleaved: n' = jrow*4 + g  <- row g*H + jrow.
__global__ __launch_bounds__(256) void build_weff(const float* __restrict__ W,
                                                  const float* __restrict__ W_ih,
                                                  const float* __restrict__ W_out,
                                                  u16* __restrict__ Wz) {
  int id = blockIdx.x * 256 + threadIdx.x;     // chunk id, total 2M
  int lane = id & 63;
  int k32  = (id >> 6) & 63;
  int n16  = id >> 12;
  int np = n16 * 16 + (lane & 15);
  int k  = k32 * 32 + (lane >> 4) * 8;
  int g = np & 3, jrow = np >> 2;
  int src = g * H_DIM + jrow;
  float wi0 = W_ih[src * 2 + 0], wi1 = W_ih[src * 2 + 1];
  const float* sw = W + (size_t)src * H_DIM + k;
  u16 out[8];
  for (int j = 0; j < 8; ++j) {
    float v = sw[j] + wi0 * W_out[k + j] + wi1 * W_out[H_DIM + k + j];
    out[j] = f2b(v);
  }
  u16* dst = Wz + (size_t)id * 8;
  *(ushort4*)(dst) = *(ushort4*)&out[0];
  *(ushort4*)(dst + 4) = *(ushort4*)&out[4];
}

// epi[n'] = {b_ih+b_hh+b_out@W_ih^T, W_ih[:,0], W_ih[:,1], 0} at interleaved n'
__global__ __launch_bounds__(256) void build_epi(const float* __restrict__ b_ih,
                                                 const float* __restrict__ b_hh,
                                                 const float* __restrict__ W_ih,
                                                 const float* __restrict__ b_out,
                                                 float* __restrict__ epi) {
  int np = blockIdx.x * 256 + threadIdx.x;
  int src = (np & 3) * H_DIM + (np >> 2);
  float wi0 = W_ih[src * 2 + 0], wi1 = W_ih[src * 2 + 1];
  float4 e;
  e.x = b_ih[src] + b_hh[src] + b_out[0] * wi0 + b_out[1] * wi1;
  e.y = wi0;
  e.z = wi1;
  e.w = 0.f;
  ((float4*)epi)[np] = e;
}

// ---- plain GEMM (h0 path, runs once) ----
#define BM 64
#define BN 128
#define BK 32
__global__ __launch_bounds__(256) void gemm_bt(const u16* __restrict__ A,
                                               const u16* __restrict__ Bm,
                                               float* __restrict__ C,
                                               int M, int N, int K) {
  __shared__ u16 sA[BM * BK];
  __shared__ u16 sB[BN * BK];
  const int t = threadIdx.x;
  const int bm0 = blockIdx.y * BM, bn0 = blockIdx.x * BN;
  const int wave = t >> 6, lane = t & 63;
  const int wm = (wave >> 1) * 32, wn = (wave & 1) * 64;
  const int r16 = lane & 15, quad = lane >> 4;

  f32x4 acc[2][4];
  const f32x4 z = {0.f, 0.f, 0.f, 0.f};
  for (int i = 0; i < 2; ++i)
    for (int j = 0; j < 4; ++j) acc[i][j] = z;

  const int arow = t >> 2, acg = t & 3;

  for (int k0 = 0; k0 < K; k0 += BK) {
    __syncthreads();
    *(uint4*)&sA[arow * BK + acg * 8] =
        *(const uint4*)&A[(size_t)(bm0 + arow) * K + k0 + acg * 8];
    for (int i = 0; i < 2; ++i) {
      int c = t + 256 * i;
      int row = c >> 2, cg = c & 3;
      *(uint4*)&sB[row * BK + cg * 8] =
          *(const uint4*)&Bm[(size_t)(bn0 + row) * K + k0 + cg * 8];
    }
    __syncthreads();
    bf16x8 af[2], bfr[4];
    for (int mt = 0; mt < 2; ++mt)
      af[mt] = *(const bf16x8*)&sA[(wm + mt * 16 + r16) * BK + quad * 8];
    for (int nt = 0; nt < 4; ++nt)
      bfr[nt] = *(const bf16x8*)&sB[(wn + nt * 16 + r16) * BK + quad * 8];
    for (int mt = 0; mt < 2; ++mt)
      for (int nt = 0; nt < 4; ++nt)
        acc[mt][nt] = __builtin_amdgcn_mfma_f32_16x16x32_bf16(af[mt], bfr[nt],
                                                              acc[mt][nt], 0, 0, 0);
  }
  for (int mt = 0; mt < 2; ++mt)
    for (int nt = 0; nt < 4; ++nt) {
      int row = bm0 + wm + mt * 16 + quad * 4;
      int col = bn0 + wn + nt * 16 + r16;
      for (int r = 0; r < 4; ++r)
        C[(size_t)(row + r) * N + col] = acc[mt][nt][r];
    }
}

// h0pre + b_embed -> h fragment layout.
// chunk = ((m>>4)*64 + (k>>5))*64 + ((k>>3)&3)*16 + (m&15), elem k&7
__global__ __launch_bounds__(256) void init_state(const float* __restrict__ h0pre,
                                                  const float* __restrict__ b_embed,
                                                  u16* __restrict__ h) {
  int idx = blockIdx.x * 256 + threadIdx.x;  // B*H
  int bg = idx >> 11, k = idx & (H_DIM - 1);
  float v = h0pre[idx] + b_embed[k];
  size_t chunk = (((size_t)(bg >> 4)) * 64 + (k >> 5)) * 64 + ((k >> 3) & 3) * 16 + (bg & 15);
  h[chunk * 8 + (k & 7)] = f2b(v);
}

// xcorr[m] = -(h0[m] @ W_out^T + b_out)  (step-1 correction for the fold)
__global__ __launch_bounds__(64) void calc_xcorr(const float* __restrict__ h0pre,
                                                 const float* __restrict__ b_embed,
                                                 const float* __restrict__ W_out,
                                                 const float* __restrict__ b_out,
                                                 float* __restrict__ xc) {
  int m = blockIdx.x, ln = threadIdx.x;
  float s0 = 0.f, s1 = 0.f;
  for (int k = ln; k < H_DIM; k += 64) {
    float hv = h0pre[(size_t)m * H_DIM + k] + b_embed[k];
    s0 += hv * W_out[k];
    s1 += hv * W_out[H_DIM + k];
  }
  for (int off = 32; off > 0; off >>= 1) {
    s0 += __shfl_down(s0, off);
    s1 += __shfl_down(s1, off);
  }
  if (ln == 0) {
    xc[m * 2 + 0] = -(s0 + b_out[0]);
    xc[m * 2 + 1] = -(s1 + b_out[1]);
  }
}

// out_head for one batch (m = blk*2 + wv), lanes = k32, wave-wide reduction
__device__ inline void head_2batch(const u16* __restrict__ h, int m, int ln,
                                   const float* __restrict__ W_out,
                                   const float* __restrict__ b_out,
                                   const float* __restrict__ W_stop,
                                   const float* __restrict__ b_stop,
                                   float* __restrict__ coords,
                                   float* __restrict__ stops, int row) {
  float s0 = 0.f, s1 = 0.f, s2 = 0.f;
  const int kb0 = ln * 32;
  for (int qd = 0; qd < 4; ++qd) {
    size_t ch = (((size_t)(m >> 4)) * 64 + ln) * 64 + qd * 16 + (m & 15);
    bf16x8 h8 = *(const bf16x8*)(h + ch * 8);
    int kb = kb0 + qd * 8;
    for (int j = 0; j < 8; ++j) {
      float hv = b2f((u16)h8[j]);
      s0 += hv * W_out[kb + j];
      s1 += hv * W_out[H_DIM + kb + j];
      s2 += hv * W_stop[kb + j];
    }
  }
  for (int off = 32; off > 0; off >>= 1) {
    s0 += __shfl_down(s0, off);
    s1 += __shfl_down(s1, off);
    s2 += __shfl_down(s2, off);
  }
  if (ln == 0) {
    coords[((size_t)m * T_DIM + row) * 2 + 0] = s0 + b_out[0];
    coords[((size_t)m * T_DIM + row) * 2 + 1] = s1 + b_out[1];
    stops[(size_t)m * T_DIM + row] = 1.f / (1.f + __expf(-(s2 + b_stop[0])));
  }
}

// ---- persistent kernel: all 256 steps, W_eff slice in LDS, c in registers ----
// 256 blocks x 512 threads (1 block/CU). Block owns n' cols [blk*32, blk*32+32)
// = h-cols [blk*8, blk*8+8). Wave wv owns m-rows [wv*64, wv*64+64).
__global__ __launch_bounds__(512, 2) void persist(
    const u16* __restrict__ Wz, u16* __restrict__ hb0, u16* __restrict__ hb1,
    const float* __restrict__ epi, const float* __restrict__ xc,
    const float* __restrict__ W_out, const float* __restrict__ b_out,
    const float* __restrict__ W_stop, const float* __restrict__ b_stop,
    float* __restrict__ coords, float* __restrict__ stops) {
  __shared__ char smem[149504];                // 128 KB W + 18 KB gate scratch
  cg::grid_group grid = cg::this_grid();
  const int blk = blockIdx.x, t = threadIdx.x, wv = t >> 6, ln = t & 63;
  const int r16 = ln & 15, quad = ln >> 4;

  // stage W_eff slice: n16 tiles {2blk, 2blk+1} = 8192 chunks = 128 KB
  {
    const uint4* wg = (const uint4*)Wz + (size_t)blk * 8192;
    uint4* wl = (uint4*)smem;
    for (int i = 0; i < 16; ++i) wl[i * 512 + t] = wg[(size_t)i * 512 + t];
  }
  __syncthreads();
  const bf16x8* bW = (const bf16x8*)smem;      // [ni*4096 + k32*64 + ln]
  float* sc = (float*)(smem + 131072);         // 128 x 36 f32 gate scratch
  const float4* epi4 = (const float4*)epi;

  float cst[8];
  for (int j = 0; j < 8; ++j) cst[j] = 0.f;

  for (int s = 1; s <= T_DIM; ++s) {
    const u16* hin = (s & 1) ? hb0 : hb1;      // h(s-1)
    u16* hout = (s & 1) ? hb1 : hb0;           // h(s)

    if (s >= 2 && wv < 2)                      // out_head for h(s-1), spread on all blocks
      head_2batch(hin, blk * 2 + wv, ln, W_out, b_out, W_stop, b_stop,
                  coords, stops, s - 2);

    // K-loop: A from global (frag layout), B from LDS; no block barrier
    f32x4 acc[4][2];
    const f32x4 z = {0.f, 0.f, 0.f, 0.f};
    for (int i = 0; i < 4; ++i) { acc[i][0] = z; acc[i][1] = z; }

    const u16* aB[4];
    for (int mi = 0; mi < 4; ++mi)
      aB[mi] = hin + (size_t)(4 * wv + mi) * 32768 + ln * 8;

    bf16x8 a[2][4], b[2][2];
    for (int mi = 0; mi < 4; ++mi) a[0][mi] = *(const bf16x8*)(aB[mi]);
    for (int ni = 0; ni < 2; ++ni) b[0][ni] = bW[ni * 4096 + ln];

    for (int k32 = 0; k32 < 64; ++k32) {
      const int cu = k32 & 1;
      if (k32 < 63) {
        const int nx = cu ^ 1, kn = k32 + 1;
        for (int mi = 0; mi < 4; ++mi)
          a[nx][mi] = *(const bf16x8*)(aB[mi] + (size_t)kn * 512);
        for (int ni = 0; ni < 2; ++ni)
          b[nx][ni] = bW[ni * 4096 + kn * 64 + ln];
      }
      for (int mi = 0; mi < 4; ++mi)
        for (int ni = 0; ni < 2; ++ni)
          acc[mi][ni] = __builtin_amdgcn_mfma_f32_16x16x32_bf16(a[cu][mi], b[cu][ni],
                                                                acc[mi][ni], 0, 0, 0);
    }

    // epilogue: 4 rounds of 128 m-rows through LDS scratch (stride 36)
    for (int r = 0; r < 4; ++r) {
      __syncthreads();
      if ((wv >> 1) == r) {                    // writer waves 2r, 2r+1
        for (int mi = 0; mi < 4; ++mi)
          for (int ni = 0; ni < 2; ++ni) {
            int row = (wv & 1) * 64 + mi * 16 + quad * 4;
            int col = ni * 16 + r16;
            for (int rr = 0; rr < 4; ++rr)
              sc[(row + rr) * 36 + col] = acc[mi][ni][rr];
          }
      }
      __syncthreads();
      if ((t >> 7) == r) {                     // reader threads: m-row = t
        const int row = t & 127;
        float x0 = 0.f, x1 = 0.f;
        if (s == 1) { x0 = xc[t * 2 + 0]; x1 = xc[t * 2 + 1]; }
        u16x8 hv;
        for (int j = 0; j < 8; ++j) {
          float4 g4 = *(const float4*)&sc[row * 36 + 4 * j];
          float4 e0 = epi4[blk * 32 + 4 * j + 0];
          float4 e1 = epi4[blk * 32 + 4 * j + 1];
          float4 e2 = epi4[blk * 32 + 4 * j + 2];
          float4 e3 = epi4[blk * 32 + 4 * j + 3];
          float gi = g4.x + e0.x + x0 * e0.y + x1 * e0.z;
          float gf = g4.y + e1.x + x0 * e1.y + x1 * e1.z;
          float gg = g4.z + e2.x + x0 * e2.y + x1 * e2.z;
          float go = g4.w + e3.x + x0 * e3.y + x1 * e3.z;
          float si = 1.f / (1.f + __expf(-gi));
          float sf = 1.f / (1.f + __expf(-gf));
          float so = 1.f / (1.f + __expf(-go));
          float cn = sf * cst[j] + si * tanhf(gg);
          cst[j] = cn;
          hv[j] = f2b(so * tanhf(cn));
        }
        // h-col base = blk*8: chunk = ((m>>4)*64 + (blk>>2))*64 + (blk&3)*16 + (m&15)
        size_t ch = (((size_t)(t >> 4)) * 64 + (blk >> 2)) * 64 + (blk & 3) * 16 + (t & 15);
        *(u16x8*)(hout + ch * 8) = hv;
      }
    }
    grid.sync();
  }

  // final out_head: h(256) lives in hb0 (256 even)
  if (wv < 2)
    head_2batch(hb0, blk * 2 + wv, ln, W_out, b_out, W_stop, b_stop,
                coords, stops, T_DIM - 1);
}

extern "C" void kernel_launch(void* const* d_in, const int* in_sizes, int n_in,
                              void* d_out, int out_size, void* d_ws, size_t ws_size,
                              hipStream_t stream) {
  const float* embedding = (const float*)d_in[0];
  const float* W_embed   = (const float*)d_in[2];
  const float* b_embed   = (const float*)d_in[3];
  const float* W_ih      = (const float*)d_in[4];
  const float* b_ih      = (const float*)d_in[5];
  const float* W_hh      = (const float*)d_in[6];
  const float* b_hh      = (const float*)d_in[7];
  const float* W_out     = (const float*)d_in[8];
  const float* b_out     = (const float*)d_in[9];
  const float* W_stop    = (const float*)d_in[10];
  const float* b_stop    = (const float*)d_in[11];

  float* coords = (float*)d_out;
  float* stops  = (float*)d_out + (size_t)B_DIM * T_DIM * 2;

  char* ws = (char*)d_ws;
  u16* W_z     = (u16*)ws;   ws += (size_t)G4H * H_DIM * 2;    // 32 MB
  u16* W_emb_b = (u16*)ws;   ws += (size_t)H_DIM * E_DIM * 2;  // 8 MB
  u16* emb_b   = (u16*)ws;   ws += (size_t)B_DIM * E_DIM * 2;  // 2 MB
  float* h0pre = (float*)ws; ws += (size_t)B_DIM * H_DIM * 4;  // 4 MB
  float* epi   = (float*)ws; ws += (size_t)G4H * 4 * 4;        // 128 KB
  u16* hbuf0   = (u16*)ws;   ws += (size_t)B_DIM * H_DIM * 2;  // 2 MB
  u16* hbuf1   = (u16*)ws;   ws += (size_t)B_DIM * H_DIM * 2;  // 2 MB
  float* xcorr = (float*)ws; ws += (size_t)B_DIM * 2 * 4;

  convert_bf16<<<(B_DIM * E_DIM / 4 + 255) / 256, 256, 0, stream>>>(embedding, emb_b, B_DIM * E_DIM / 4);
  convert_bf16<<<(H_DIM * E_DIM / 4 + 255) / 256, 256, 0, stream>>>(W_embed, W_emb_b, H_DIM * E_DIM / 4);
  build_weff<<<(G4H * H_DIM / 8) / 256, 256, 0, stream>>>(W_hh, W_ih, W_out, W_z);
  build_epi<<<G4H / 256, 256, 0, stream>>>(b_ih, b_hh, W_ih, b_out, epi);

  gemm_bt<<<dim3(H_DIM / BN, B_DIM / BM), 256, 0, stream>>>(emb_b, W_emb_b, h0pre,
                                                            B_DIM, H_DIM, E_DIM);
  init_state<<<(B_DIM * H_DIM) / 256, 256, 0, stream>>>(h0pre, b_embed, hbuf0);
  calc_xcorr<<<B_DIM, 64, 0, stream>>>(h0pre, b_embed, W_out, b_out, xcorr);

  void* kargs[] = {(void*)&W_z, (void*)&hbuf0, (void*)&hbuf1, (void*)&epi,
                   (void*)&xcorr, (void*)&W_out, (void*)&b_out, (void*)&W_stop,
                   (void*)&b_stop, (void*)&coords, (void*)&stops};
  hipLaunchCooperativeKernel((void*)persist, dim3(256), dim3(512), kargs, 0, stream);
}

// Round 6
// 8286.854 us; speedup vs baseline: 2.2865x; 2.2865x over previous
//
#include <hip/hip_runtime.h>
#include <stdint.h>

#define E_DIM 2048
#define H_DIM 2048
#define B_DIM 512
#define T_DIM 256
#define G4H   8192  // 4*H

typedef unsigned short u16;
typedef __attribute__((ext_vector_type(8))) short bf16x8;
typedef __attribute__((ext_vector_type(4))) float f32x4;

__device__ inline u16 f2b(float f) {
  union { float f; uint32_t i; } v; v.f = f;
  uint32_t u = v.i;
  return (u16)((u + 0x7FFFu + ((u >> 16) & 1u)) >> 16);  // RNE
}
__device__ inline float b2f(u16 u) {
  union { uint32_t i; float f; } v; v.i = ((uint32_t)u) << 16; return v.f;
}

__global__ __launch_bounds__(256) void convert_bf16(const float* __restrict__ s,
                                                    u16* __restrict__ d, int n4) {
  int i = blockIdx.x * 256 + threadIdx.x;
  if (i < n4) {
    float4 f = ((const float4*)s)[i];
    ushort4 o;
    o.x = f2b(f.x); o.y = f2b(f.y); o.z = f2b(f.z); o.w = f2b(f.w);
    ((ushort4*)d)[i] = o;
  }
}

// W_eff = W_hh + W_ih @ W_out (rank-2 fold), in MFMA-B-fragment order.
// Chunk id = (n16*64 + k32)*64 + lane holds 8 bf16 of
//   B[n' = n16*16 + (lane&15)][k = k32*32 + (lane>>4)*8 + j]
// n' gate-interleaved: n' = jrow*4 + g  <- row g*H + jrow.   [verified r5]
__global__ __launch_bounds__(256) void build_weff(const float* __restrict__ W,
                                                  const float* __restrict__ W_ih,
                                                  const float* __restrict__ W_out,
                                                  u16* __restrict__ Wz) {
  int id = blockIdx.x * 256 + threadIdx.x;     // chunk id, total 2M
  int lane = id & 63;
  int k32  = (id >> 6) & 63;
  int n16  = id >> 12;
  int np = n16 * 16 + (lane & 15);
  int k  = k32 * 32 + (lane >> 4) * 8;
  int g = np & 3, jrow = np >> 2;
  int src = g * H_DIM + jrow;
  float wi0 = W_ih[src * 2 + 0], wi1 = W_ih[src * 2 + 1];
  const float* sw = W + (size_t)src * H_DIM + k;
  u16 out[8];
  for (int j = 0; j < 8; ++j) {
    float v = sw[j] + wi0 * W_out[k + j] + wi1 * W_out[H_DIM + k + j];
    out[j] = f2b(v);
  }
  u16* dst = Wz + (size_t)id * 8;
  *(ushort4*)(dst) = *(ushort4*)&out[0];
  *(ushort4*)(dst + 4) = *(ushort4*)&out[4];
}

// epi[n'] = {b_ih+b_hh+b_out@W_ih^T, W_ih[:,0], W_ih[:,1], 0}   [verified r5]
__global__ __launch_bounds__(256) void build_epi(const float* __restrict__ b_ih,
                                                 const float* __restrict__ b_hh,
                                                 const float* __restrict__ W_ih,
                                                 const float* __restrict__ b_out,
                                                 float* __restrict__ epi) {
  int np = blockIdx.x * 256 + threadIdx.x;
  int src = (np & 3) * H_DIM + (np >> 2);
  float wi0 = W_ih[src * 2 + 0], wi1 = W_ih[src * 2 + 1];
  float4 e;
  e.x = b_ih[src] + b_hh[src] + b_out[0] * wi0 + b_out[1] * wi1;
  e.y = wi0;
  e.z = wi1;
  e.w = 0.f;
  ((float4*)epi)[np] = e;
}

// ---- plain GEMM (h0 path, runs once) ----
#define BM 64
#define BN 128
#define BK 32
__global__ __launch_bounds__(256) void gemm_bt(const u16* __restrict__ A,
                                               const u16* __restrict__ Bm,
                                               float* __restrict__ C,
                                               int M, int N, int K) {
  __shared__ u16 sA[BM * BK];
  __shared__ u16 sB[BN * BK];
  const int t = threadIdx.x;
  const int bm0 = blockIdx.y * BM, bn0 = blockIdx.x * BN;
  const int wave = t >> 6, lane = t & 63;
  const int wm = (wave >> 1) * 32, wn = (wave & 1) * 64;
  const int r16 = lane & 15, quad = lane >> 4;

  f32x4 acc[2][4];
  const f32x4 z = {0.f, 0.f, 0.f, 0.f};
  for (int i = 0; i < 2; ++i)
    for (int j = 0; j < 4; ++j) acc[i][j] = z;

  const int arow = t >> 2, acg = t & 3;

  for (int k0 = 0; k0 < K; k0 += BK) {
    __syncthreads();
    *(uint4*)&sA[arow * BK + acg * 8] =
        *(const uint4*)&A[(size_t)(bm0 + arow) * K + k0 + acg * 8];
    for (int i = 0; i < 2; ++i) {
      int c = t + 256 * i;
      int row = c >> 2, cg = c & 3;
      *(uint4*)&sB[row * BK + cg * 8] =
          *(const uint4*)&Bm[(size_t)(bn0 + row) * K + k0 + cg * 8];
    }
    __syncthreads();
    bf16x8 af[2], bfr[4];
    for (int mt = 0; mt < 2; ++mt)
      af[mt] = *(const bf16x8*)&sA[(wm + mt * 16 + r16) * BK + quad * 8];
    for (int nt = 0; nt < 4; ++nt)
      bfr[nt] = *(const bf16x8*)&sB[(wn + nt * 16 + r16) * BK + quad * 8];
    for (int mt = 0; mt < 2; ++mt)
      for (int nt = 0; nt < 4; ++nt)
        acc[mt][nt] = __builtin_amdgcn_mfma_f32_16x16x32_bf16(af[mt], bfr[nt],
                                                              acc[mt][nt], 0, 0, 0);
  }
  for (int mt = 0; mt < 2; ++mt)
    for (int nt = 0; nt < 4; ++nt) {
      int row = bm0 + wm + mt * 16 + quad * 4;
      int col = bn0 + wn + nt * 16 + r16;
      for (int r = 0; r < 4; ++r)
        C[(size_t)(row + r) * N + col] = acc[mt][nt][r];
    }
}

// h0pre + b_embed -> h fragment layout; c=0; xzero=0.
__global__ __launch_bounds__(256) void init_state(const float* __restrict__ h0pre,
                                                  const float* __restrict__ b_embed,
                                                  u16* __restrict__ h,
                                                  float* __restrict__ c,
                                                  float* __restrict__ xzero) {
  int idx = blockIdx.x * 256 + threadIdx.x;  // B*H
  int bg = idx >> 11, k = idx & (H_DIM - 1);
  float v = h0pre[idx] + b_embed[k];
  size_t chunk = (((size_t)(bg >> 4)) * 64 + (k >> 5)) * 64 + ((k >> 3) & 3) * 16 + (bg & 15);
  size_t pos = chunk * 8 + (k & 7);
  h[pos] = f2b(v);
  c[pos] = 0.f;
  if (idx < B_DIM * 2) xzero[idx] = 0.f;
}

// xcorr[m] = -(h0[m] @ W_out^T + b_out)  (step-1 correction)   [verified r5]
__global__ __launch_bounds__(64) void calc_xcorr(const float* __restrict__ h0pre,
                                                 const float* __restrict__ b_embed,
                                                 const float* __restrict__ W_out,
                                                 const float* __restrict__ b_out,
                                                 float* __restrict__ xc) {
  int m = blockIdx.x, ln = threadIdx.x;
  float s0 = 0.f, s1 = 0.f;
  for (int k = ln; k < H_DIM; k += 64) {
    float hv = h0pre[(size_t)m * H_DIM + k] + b_embed[k];
    s0 += hv * W_out[k];
    s1 += hv * W_out[H_DIM + k];
  }
  for (int off = 32; off > 0; off >>= 1) {
    s0 += __shfl_down(s0, off);
    s1 += __shfl_down(s1, off);
  }
  if (ln == 0) {
    xc[m * 2 + 0] = -(s0 + b_out[0]);
    xc[m * 2 + 1] = -(s1 + b_out[1]);
  }
}

// seed outputs: coords[m][t] = b_out, stop-logit[m][t] = b_stop (atomics add onto these)
__global__ __launch_bounds__(256) void init_out(const float* __restrict__ b_out,
                                                const float* __restrict__ b_stop,
                                                float* __restrict__ coords,
                                                float* __restrict__ stops) {
  int i = blockIdx.x * 256 + threadIdx.x;      // B*T
  coords[i * 2 + 0] = b_out[0];
  coords[i * 2 + 1] = b_out[1];
  stops[i] = b_stop[0];
}

__global__ __launch_bounds__(256) void finalize_stops(float* __restrict__ stops) {
  int i = blockIdx.x * 256 + threadIdx.x;      // B*T
  stops[i] = 1.f / (1.f + __expf(-stops[i]));
}

// ---- fused step: r4 GEMM core + LSTM epilogue + in-epilogue output heads ----
// 8 waves: q = wv&3 quadrant (qm,qn), kh = wv>>2 K-half; K-combine via LDS.
// Heads: computed on fresh fp32 h, quad-shuffle-reduced, atomicAdd to out.
__global__ __launch_bounds__(512) void gemm_lstm(const u16* __restrict__ hA,
                                                 const u16* __restrict__ Wz,
                                                 const float* __restrict__ epi,
                                                 const float* __restrict__ x,
                                                 float* __restrict__ c,
                                                 u16* __restrict__ h_out,
                                                 const float* __restrict__ W_out,
                                                 const float* __restrict__ W_stop,
                                                 float* __restrict__ coords,
                                                 float* __restrict__ stops,
                                                 int trow) {
  __shared__ char smem[33792];
  float* gt   = (float*)smem;    // 64 x 132 f32 epilogue tile
  float* comb = (float*)smem;    // 2 x 4096 f32 combine buffers

  const int bid = blockIdx.x;
  const int nt = (bid & 7) * 8 + ((bid >> 3) & 7);   // XCD-pinned n-tile
  const int mt = bid >> 6;
  const int bm0 = mt * 128;

  const int t = threadIdx.x, wv = t >> 6, ln = t & 63;
  const int q = wv & 3, kh = wv >> 2;
  const int qm = q & 1, qn = q >> 1;
  const int r16 = ln & 15, quad = ln >> 4;

  const u16* pA[4];
  const u16* pB[4];
  for (int i = 0; i < 4; ++i) {
    pA[i] = hA + (size_t)((bm0 >> 4) + qm * 4 + i) * 32768 +
            (size_t)(kh * 32) * 512 + ln * 8;
    pB[i] = Wz + (size_t)(nt * 8 + qn * 4 + i) * 32768 +
            (size_t)(kh * 32) * 512 + ln * 8;
  }

  f32x4 acc[4][4];
  const f32x4 z = {0.f, 0.f, 0.f, 0.f};
  for (int i = 0; i < 4; ++i)
    for (int j = 0; j < 4; ++j) acc[i][j] = z;

  bf16x8 af[2][4], bf[2][4];
  for (int i = 0; i < 4; ++i) {
    af[0][i] = *(const bf16x8*)(pA[i]);
    bf[0][i] = *(const bf16x8*)(pB[i]);
  }

#pragma unroll 2
  for (int kk = 0; kk < 32; ++kk) {
    const int s = kk & 1;
    if (kk + 1 < 32) {
      const int sp = s ^ 1;
      for (int i = 0; i < 4; ++i) {
        af[sp][i] = *(const bf16x8*)(pA[i] + (size_t)(kk + 1) * 512);
        bf[sp][i] = *(const bf16x8*)(pB[i] + (size_t)(kk + 1) * 512);
      }
    }
    for (int mi = 0; mi < 4; ++mi)
      for (int ni = 0; ni < 4; ++ni)
        acc[mi][ni] = __builtin_amdgcn_mfma_f32_16x16x32_bf16(af[s][mi], bf[s][ni],
                                                              acc[mi][ni], 0, 0, 0);
  }

  // combine K-halves: kh=1 exports via LDS, kh=0 adds (2 rounds by qn)
  for (int r = 0; r < 2; ++r) {
    __syncthreads();
    if (kh == 1 && qn == r) {
      float* dst = comb + qm * 4096;
      for (int mi = 0; mi < 4; ++mi)
        for (int ni = 0; ni < 4; ++ni)
          *(f32x4*)&dst[((mi * 4 + ni) * 64 + ln) * 4] = acc[mi][ni];
    }
    __syncthreads();
    if (kh == 0 && qn == r) {
      const float* src = comb + qm * 4096;
      for (int mi = 0; mi < 4; ++mi)
        for (int ni = 0; ni < 4; ++ni) {
          f32x4 p = *(const f32x4*)&src[((mi * 4 + ni) * 64 + ln) * 4];
          acc[mi][ni] += p;
        }
    }
  }

  // epilogue in two 64-row halves; heads fused
  for (int half = 0; half < 2; ++half) {
    __syncthreads();
    if (kh == 0 && qm == half) {               // 2 writer waves (qn = 0,1)
      for (int mi = 0; mi < 4; ++mi)
        for (int ni = 0; ni < 4; ++ni) {
          int row = mi * 16 + quad * 4;
          int col = qn * 64 + ni * 16 + r16;
          for (int r = 0; r < 4; ++r)
            gt[(row + r) * 132 + col] = acc[mi][ni][r];
        }
    }
    __syncthreads();
    if (kh == half) {                          // 4 reader waves
      const int lrow = q * 16 + r16;           // 0..63
      const int bg = bm0 + half * 64 + lrow;
      const float x0 = x[bg * 2 + 0], x1 = x[bg * 2 + 1];
      const size_t chunk = (((size_t)(bg >> 4)) * 64 + nt) * 64 + ln;
      // this thread's h-cols: hc0 + 0..7 where hc0 = nt*32 + quad*8
      const int hc0 = nt * 32 + quad * 8;
      float cv[8]; u16 hv[8];
      float s0 = 0.f, s1 = 0.f, s2 = 0.f;
      const float4* epi4 = (const float4*)epi;
      for (int j = 0; j < 8; ++j) {
        int col = quad * 32 + j * 4;
        float4 g4 = *(const float4*)&gt[lrow * 132 + col];
        float4 e0 = epi4[nt * 128 + col + 0];
        float4 e1 = epi4[nt * 128 + col + 1];
        float4 e2 = epi4[nt * 128 + col + 2];
        float4 e3 = epi4[nt * 128 + col + 3];
        float gi = g4.x + e0.x + x0 * e0.y + x1 * e0.z;
        float gf = g4.y + e1.x + x0 * e1.y + x1 * e1.z;
        float gg = g4.z + e2.x + x0 * e2.y + x1 * e2.z;
        float go = g4.w + e3.x + x0 * e3.y + x1 * e3.z;
        float si = 1.f / (1.f + __expf(-gi));
        float sf = 1.f / (1.f + __expf(-gf));
        float so = 1.f / (1.f + __expf(-go));
        float cn = sf * c[chunk * 8 + j] + si * tanhf(gg);
        cv[j] = cn;
        float hf = so * tanhf(cn);
        hv[j] = f2b(hf);
        s0 += hf * W_out[hc0 + j];
        s1 += hf * W_out[H_DIM + hc0 + j];
        s2 += hf * W_stop[hc0 + j];
      }
      *(float4*)&c[chunk * 8 + 0] = *(float4*)&cv[0];
      *(float4*)&c[chunk * 8 + 4] = *(float4*)&cv[4];
      *(ushort4*)&h_out[chunk * 8 + 0] = *(ushort4*)&hv[0];
      *(ushort4*)&h_out[chunk * 8 + 4] = *(ushort4*)&hv[4];
      // reduce over quad (lanes ln, ln^16, ln^32 span quad 0..3 at fixed r16)
      s0 += __shfl_xor(s0, 16); s1 += __shfl_xor(s1, 16); s2 += __shfl_xor(s2, 16);
      s0 += __shfl_xor(s0, 32); s1 += __shfl_xor(s1, 32); s2 += __shfl_xor(s2, 32);
      if (quad == 0) {
        atomicAdd(&coords[((size_t)bg * T_DIM + trow) * 2 + 0], s0);
        atomicAdd(&coords[((size_t)bg * T_DIM + trow) * 2 + 1], s1);
        atomicAdd(&stops[(size_t)bg * T_DIM + trow], s2);
      }
    }
  }
}

extern "C" void kernel_launch(void* const* d_in, const int* in_sizes, int n_in,
                              void* d_out, int out_size, void* d_ws, size_t ws_size,
                              hipStream_t stream) {
  const float* embedding = (const float*)d_in[0];
  const float* W_embed   = (const float*)d_in[2];
  const float* b_embed   = (const float*)d_in[3];
  const float* W_ih      = (const float*)d_in[4];
  const float* b_ih      = (const float*)d_in[5];
  const float* W_hh      = (const float*)d_in[6];
  const float* b_hh      = (const float*)d_in[7];
  const float* W_out     = (const float*)d_in[8];
  const float* b_out     = (const float*)d_in[9];
  const float* W_stop    = (const float*)d_in[10];
  const float* b_stop    = (const float*)d_in[11];

  float* coords = (float*)d_out;
  float* stops  = (float*)d_out + (size_t)B_DIM * T_DIM * 2;

  char* ws = (char*)d_ws;
  u16* W_z     = (u16*)ws;   ws += (size_t)G4H * H_DIM * 2;    // 32 MB
  u16* W_emb_b = (u16*)ws;   ws += (size_t)H_DIM * E_DIM * 2;  // 8 MB
  u16* emb_b   = (u16*)ws;   ws += (size_t)B_DIM * E_DIM * 2;  // 2 MB
  float* h0pre = (float*)ws; ws += (size_t)B_DIM * H_DIM * 4;  // 4 MB
  float* epi   = (float*)ws; ws += (size_t)G4H * 4 * 4;        // 128 KB
  float* cbuf  = (float*)ws; ws += (size_t)B_DIM * H_DIM * 4;  // 4 MB
  u16* hbuf0   = (u16*)ws;   ws += (size_t)B_DIM * H_DIM * 2;  // 2 MB
  u16* hbuf1   = (u16*)ws;   ws += (size_t)B_DIM * H_DIM * 2;  // 2 MB
  float* xcorr = (float*)ws; ws += (size_t)B_DIM * 2 * 4;
  float* xzero = (float*)ws; ws += (size_t)B_DIM * 2 * 4;

  convert_bf16<<<(B_DIM * E_DIM / 4 + 255) / 256, 256, 0, stream>>>(embedding, emb_b, B_DIM * E_DIM / 4);
  convert_bf16<<<(H_DIM * E_DIM / 4 + 255) / 256, 256, 0, stream>>>(W_embed, W_emb_b, H_DIM * E_DIM / 4);
  build_weff<<<(G4H * H_DIM / 8) / 256, 256, 0, stream>>>(W_hh, W_ih, W_out, W_z);
  build_epi<<<G4H / 256, 256, 0, stream>>>(b_ih, b_hh, W_ih, b_out, epi);
  init_out<<<(B_DIM * T_DIM) / 256, 256, 0, stream>>>(b_out, b_stop, coords, stops);

  gemm_bt<<<dim3(H_DIM / BN, B_DIM / BM), 256, 0, stream>>>(emb_b, W_emb_b, h0pre,
                                                            B_DIM, H_DIM, E_DIM);
  init_state<<<(B_DIM * H_DIM) / 256, 256, 0, stream>>>(h0pre, b_embed, hbuf0, cbuf, xzero);
  calc_xcorr<<<B_DIM, 64, 0, stream>>>(h0pre, b_embed, W_out, b_out, xcorr);

  for (int t = 0; t < T_DIM; ++t) {
    u16* h_in  = (t & 1) ? hbuf1 : hbuf0;
    u16* h_out = (t & 1) ? hbuf0 : hbuf1;
    const float* xv = (t == 0) ? xcorr : xzero;
    gemm_lstm<<<256, 512, 0, stream>>>(h_in, W_z, epi, xv, cbuf, h_out,
                                       W_out, W_stop, coords, stops, t);
  }
  finalize_stops<<<(B_DIM * T_DIM) / 256, 256, 0, stream>>>(stops);
}

// Round 7
// 7817.654 us; speedup vs baseline: 2.4237x; 1.0600x over previous
//
#include <hip/hip_runtime.h>
#include <stdint.h>

#define E_DIM 2048
#define H_DIM 2048
#define B_DIM 512
#define T_DIM 256
#define G4H   8192  // 4*H

typedef unsigned short u16;
typedef __attribute__((ext_vector_type(8))) short bf16x8;
typedef __attribute__((ext_vector_type(4))) float f32x4;

__device__ inline u16 f2b(float f) {
  union { float f; uint32_t i; } v; v.f = f;
  uint32_t u = v.i;
  return (u16)((u + 0x7FFFu + ((u >> 16) & 1u)) >> 16);  // RNE
}
__device__ inline float b2f(u16 u) {
  union { uint32_t i; float f; } v; v.i = ((uint32_t)u) << 16; return v.f;
}

__global__ __launch_bounds__(256) void convert_bf16(const float* __restrict__ s,
                                                    u16* __restrict__ d, int n4) {
  int i = blockIdx.x * 256 + threadIdx.x;
  if (i < n4) {
    float4 f = ((const float4*)s)[i];
    ushort4 o;
    o.x = f2b(f.x); o.y = f2b(f.y); o.z = f2b(f.z); o.w = f2b(f.w);
    ((ushort4*)d)[i] = o;
  }
}

// W_eff = W_hh + W_ih @ W_out (rank-2 fold), MFMA-B-fragment order. [verified r5/r6]
__global__ __launch_bounds__(256) void build_weff(const float* __restrict__ W,
                                                  const float* __restrict__ W_ih,
                                                  const float* __restrict__ W_out,
                                                  u16* __restrict__ Wz) {
  int id = blockIdx.x * 256 + threadIdx.x;     // chunk id, total 2M
  int lane = id & 63;
  int k32  = (id >> 6) & 63;
  int n16  = id >> 12;
  int np = n16 * 16 + (lane & 15);
  int k  = k32 * 32 + (lane >> 4) * 8;
  int g = np & 3, jrow = np >> 2;
  int src = g * H_DIM + jrow;
  float wi0 = W_ih[src * 2 + 0], wi1 = W_ih[src * 2 + 1];
  const float* sw = W + (size_t)src * H_DIM + k;
  u16 out[8];
  for (int j = 0; j < 8; ++j) {
    float v = sw[j] + wi0 * W_out[k + j] + wi1 * W_out[H_DIM + k + j];
    out[j] = f2b(v);
  }
  u16* dst = Wz + (size_t)id * 8;
  *(ushort4*)(dst) = *(ushort4*)&out[0];
  *(ushort4*)(dst + 4) = *(ushort4*)&out[4];
}

// epi[n'] = {b_ih+b_hh+b_out@W_ih^T, W_ih[:,0], W_ih[:,1], 0}   [verified r5/r6]
__global__ __launch_bounds__(256) void build_epi(const float* __restrict__ b_ih,
                                                 const float* __restrict__ b_hh,
                                                 const float* __restrict__ W_ih,
                                                 const float* __restrict__ b_out,
                                                 float* __restrict__ epi) {
  int np = blockIdx.x * 256 + threadIdx.x;
  int src = (np & 3) * H_DIM + (np >> 2);
  float wi0 = W_ih[src * 2 + 0], wi1 = W_ih[src * 2 + 1];
  float4 e;
  e.x = b_ih[src] + b_hh[src] + b_out[0] * wi0 + b_out[1] * wi1;
  e.y = wi0;
  e.z = wi1;
  e.w = 0.f;
  ((float4*)epi)[np] = e;
}

// ---- plain GEMM (h0 path, runs once) ----
#define BM 64
#define BN 128
#define BK 32
__global__ __launch_bounds__(256) void gemm_bt(const u16* __restrict__ A,
                                               const u16* __restrict__ Bm,
                                               float* __restrict__ C,
                                               int M, int N, int K) {
  __shared__ u16 sA[BM * BK];
  __shared__ u16 sB[BN * BK];
  const int t = threadIdx.x;
  const int bm0 = blockIdx.y * BM, bn0 = blockIdx.x * BN;
  const int wave = t >> 6, lane = t & 63;
  const int wm = (wave >> 1) * 32, wn = (wave & 1) * 64;
  const int r16 = lane & 15, quad = lane >> 4;

  f32x4 acc[2][4];
  const f32x4 z = {0.f, 0.f, 0.f, 0.f};
  for (int i = 0; i < 2; ++i)
    for (int j = 0; j < 4; ++j) acc[i][j] = z;

  const int arow = t >> 2, acg = t & 3;

  for (int k0 = 0; k0 < K; k0 += BK) {
    __syncthreads();
    *(uint4*)&sA[arow * BK + acg * 8] =
        *(const uint4*)&A[(size_t)(bm0 + arow) * K + k0 + acg * 8];
    for (int i = 0; i < 2; ++i) {
      int c = t + 256 * i;
      int row = c >> 2, cg = c & 3;
      *(uint4*)&sB[row * BK + cg * 8] =
          *(const uint4*)&Bm[(size_t)(bn0 + row) * K + k0 + cg * 8];
    }
    __syncthreads();
    bf16x8 af[2], bfr[4];
    for (int mt = 0; mt < 2; ++mt)
      af[mt] = *(const bf16x8*)&sA[(wm + mt * 16 + r16) * BK + quad * 8];
    for (int nt = 0; nt < 4; ++nt)
      bfr[nt] = *(const bf16x8*)&sB[(wn + nt * 16 + r16) * BK + quad * 8];
    for (int mt = 0; mt < 2; ++mt)
      for (int nt = 0; nt < 4; ++nt)
        acc[mt][nt] = __builtin_amdgcn_mfma_f32_16x16x32_bf16(af[mt], bfr[nt],
                                                              acc[mt][nt], 0, 0, 0);
  }
  for (int mt = 0; mt < 2; ++mt)
    for (int nt = 0; nt < 4; ++nt) {
      int row = bm0 + wm + mt * 16 + quad * 4;
      int col = bn0 + wn + nt * 16 + r16;
      for (int r = 0; r < 4; ++r)
        C[(size_t)(row + r) * N + col] = acc[mt][nt][r];
    }
}

// h0pre + b_embed -> h fragment layout; c=0; xzero=0.
__global__ __launch_bounds__(256) void init_state(const float* __restrict__ h0pre,
                                                  const float* __restrict__ b_embed,
                                                  u16* __restrict__ h,
                                                  float* __restrict__ c,
                                                  float* __restrict__ xzero) {
  int idx = blockIdx.x * 256 + threadIdx.x;  // B*H
  int bg = idx >> 11, k = idx & (H_DIM - 1);
  float v = h0pre[idx] + b_embed[k];
  size_t chunk = (((size_t)(bg >> 4)) * 64 + (k >> 5)) * 64 + ((k >> 3) & 3) * 16 + (bg & 15);
  size_t pos = chunk * 8 + (k & 7);
  h[pos] = f2b(v);
  c[pos] = 0.f;
  if (idx < B_DIM * 2) xzero[idx] = 0.f;
}

// xcorr[m] = -(h0[m] @ W_out^T + b_out)   [verified r5/r6]
__global__ __launch_bounds__(64) void calc_xcorr(const float* __restrict__ h0pre,
                                                 const float* __restrict__ b_embed,
                                                 const float* __restrict__ W_out,
                                                 const float* __restrict__ b_out,
                                                 float* __restrict__ xc) {
  int m = blockIdx.x, ln = threadIdx.x;
  float s0 = 0.f, s1 = 0.f;
  for (int k = ln; k < H_DIM; k += 64) {
    float hv = h0pre[(size_t)m * H_DIM + k] + b_embed[k];
    s0 += hv * W_out[k];
    s1 += hv * W_out[H_DIM + k];
  }
  for (int off = 32; off > 0; off >>= 1) {
    s0 += __shfl_down(s0, off);
    s1 += __shfl_down(s1, off);
  }
  if (ln == 0) {
    xc[m * 2 + 0] = -(s0 + b_out[0]);
    xc[m * 2 + 1] = -(s1 + b_out[1]);
  }
}

// seed outputs with biases (epilogue atomics add partial dots onto these)
__global__ __launch_bounds__(256) void init_out(const float* __restrict__ b_out,
                                                const float* __restrict__ b_stop,
                                                float* __restrict__ coords,
                                                float* __restrict__ stops) {
  int i = blockIdx.x * 256 + threadIdx.x;      // B*T
  coords[i * 2 + 0] = b_out[0];
  coords[i * 2 + 1] = b_out[1];
  stops[i] = b_stop[0];
}

__global__ __launch_bounds__(256) void finalize_stops(float* __restrict__ stops) {
  int i = blockIdx.x * 256 + threadIdx.x;      // B*T
  stops[i] = 1.f / (1.f + __expf(-stops[i]));
}

// ---- fused step: 128x64 wave tiles, 4-way K-split, LDS combine, LSTM+heads ----
// Block tile 128(m) x 128(n'). 8 waves: wn2 = wv&1 (n-half), kq = wv>>1 (K/4).
// Per wave per kk: 8 A-frags + 4 B-frags -> 32 MFMA. B duplication-free.
__global__ __launch_bounds__(512) void gemm_lstm(const u16* __restrict__ hA,
                                                 const u16* __restrict__ Wz,
                                                 const float* __restrict__ epi,
                                                 const float* __restrict__ x,
                                                 float* __restrict__ c,
                                                 u16* __restrict__ h_out,
                                                 const float* __restrict__ W_out,
                                                 const float* __restrict__ W_stop,
                                                 float* __restrict__ coords,
                                                 float* __restrict__ stops,
                                                 int trow) {
  __shared__ char smem[131072];                // 4 x 32 KB combine bufs; gt aliased
  float* cb = (float*)smem;
  float* gt = (float*)smem;                    // 64 x 132 f32 epilogue tile

  const int bid = blockIdx.x;
  const int nt = (bid & 7) * 8 + ((bid >> 3) & 7);   // XCD-pinned n-tile
  const int mt = bid >> 6;
  const int bm0 = mt * 128;

  const int t = threadIdx.x, wv = t >> 6, ln = t & 63;
  const int wn2 = wv & 1, kq = wv >> 1;
  const int r16 = ln & 15, quad = ln >> 4;

  // fragment pointers; elem offset within tile = k32*512 + ln*8 (u16 units)
  const u16* pA[8];
  const u16* pB[4];
  for (int i = 0; i < 8; ++i)
    pA[i] = hA + (size_t)((bm0 >> 4) + i) * 32768 + (size_t)(kq * 16) * 512 + ln * 8;
  for (int i = 0; i < 4; ++i)
    pB[i] = Wz + (size_t)(nt * 8 + wn2 * 4 + i) * 32768 + (size_t)(kq * 16) * 512 + ln * 8;

  f32x4 acc[8][4];
  const f32x4 z = {0.f, 0.f, 0.f, 0.f};
  for (int i = 0; i < 8; ++i)
    for (int j = 0; j < 4; ++j) acc[i][j] = z;

  bf16x8 af[2][8], bf[2][4];
  for (int i = 0; i < 8; ++i) af[0][i] = *(const bf16x8*)(pA[i]);
  for (int i = 0; i < 4; ++i) bf[0][i] = *(const bf16x8*)(pB[i]);

#pragma unroll 2
  for (int kk = 0; kk < 16; ++kk) {
    const int cu = kk & 1;
    if (kk < 15) {
      const int nx = cu ^ 1;
      const size_t off = (size_t)(kk + 1) * 512;
      for (int i = 0; i < 8; ++i) af[nx][i] = *(const bf16x8*)(pA[i] + off);
      for (int i = 0; i < 4; ++i) bf[nx][i] = *(const bf16x8*)(pB[i] + off);
    }
    for (int mi = 0; mi < 8; ++mi)
      for (int ni = 0; ni < 4; ++ni)
        acc[mi][ni] = __builtin_amdgcn_mfma_f32_16x16x32_bf16(af[cu][mi], bf[cu][ni],
                                                              acc[mi][ni], 0, 0, 0);
  }

  // K-combine: round 1: kq 2,3 export (4 x 32 KB), kq 0,1 add
  if (kq >= 2) {
    float* dst = cb + ((kq - 2) * 2 + wn2) * 8192;
    for (int mi = 0; mi < 8; ++mi)
      for (int ni = 0; ni < 4; ++ni)
        *(f32x4*)&dst[((mi * 4 + ni) * 64 + ln) * 4] = acc[mi][ni];
  }
  __syncthreads();
  if (kq < 2) {
    const float* src = cb + (kq * 2 + wn2) * 8192;
    for (int mi = 0; mi < 8; ++mi)
      for (int ni = 0; ni < 4; ++ni)
        acc[mi][ni] += *(const f32x4*)&src[((mi * 4 + ni) * 64 + ln) * 4];
  }
  __syncthreads();
  // round 2: kq=1 exports, kq=0 adds -> kq=0 holds full-K acc
  if (kq == 1) {
    float* dst = cb + wn2 * 8192;
    for (int mi = 0; mi < 8; ++mi)
      for (int ni = 0; ni < 4; ++ni)
        *(f32x4*)&dst[((mi * 4 + ni) * 64 + ln) * 4] = acc[mi][ni];
  }
  __syncthreads();
  if (kq == 0) {
    const float* src = cb + wn2 * 8192;
    for (int mi = 0; mi < 8; ++mi)
      for (int ni = 0; ni < 4; ++ni)
        acc[mi][ni] += *(const f32x4*)&src[((mi * 4 + ni) * 64 + ln) * 4];
  }

  // epilogue in two 64-row halves; LSTM + fused heads  [structure verified r6]
  for (int half = 0; half < 2; ++half) {
    __syncthreads();
    if (wv < 2) {                              // writer waves (kq=0, wn2=0/1)
      for (int mi = 0; mi < 4; ++mi)
        for (int ni = 0; ni < 4; ++ni) {
          int row = mi * 16 + quad * 4;        // local 0..63
          int col = wn2 * 64 + ni * 16 + r16;  // 0..127
          f32x4 v = acc[half * 4 + mi][ni];
          for (int r = 0; r < 4; ++r)
            gt[(row + r) * 132 + col] = v[r];
        }
    }
    __syncthreads();
    if ((wv >> 2) == half) {                   // 4 reader waves
      const int q = wv & 3;
      const int lrow = q * 16 + r16;           // 0..63
      const int bg = bm0 + half * 64 + lrow;
      const float x0 = x[bg * 2 + 0], x1 = x[bg * 2 + 1];
      const size_t chunk = (((size_t)(bg >> 4)) * 64 + nt) * 64 + ln;
      const int hc0 = nt * 32 + quad * 8;
      float cv[8]; u16 hv[8];
      float s0 = 0.f, s1 = 0.f, s2 = 0.f;
      const float4* epi4 = (const float4*)epi;
      for (int j = 0; j < 8; ++j) {
        int col = quad * 32 + j * 4;
        float4 g4 = *(const float4*)&gt[lrow * 132 + col];
        float4 e0 = epi4[nt * 128 + col + 0];
        float4 e1 = epi4[nt * 128 + col + 1];
        float4 e2 = epi4[nt * 128 + col + 2];
        float4 e3 = epi4[nt * 128 + col + 3];
        float gi = g4.x + e0.x + x0 * e0.y + x1 * e0.z;
        float gf = g4.y + e1.x + x0 * e1.y + x1 * e1.z;
        float gg = g4.z + e2.x + x0 * e2.y + x1 * e2.z;
        float go = g4.w + e3.x + x0 * e3.y + x1 * e3.z;
        float si = 1.f / (1.f + __expf(-gi));
        float sf = 1.f / (1.f + __expf(-gf));
        float so = 1.f / (1.f + __expf(-go));
        float cn = sf * c[chunk * 8 + j] + si * tanhf(gg);
        cv[j] = cn;
        float hf = so * tanhf(cn);
        hv[j] = f2b(hf);
        s0 += hf * W_out[hc0 + j];
        s1 += hf * W_out[H_DIM + hc0 + j];
        s2 += hf * W_stop[hc0 + j];
      }
      *(float4*)&c[chunk * 8 + 0] = *(float4*)&cv[0];
      *(float4*)&c[chunk * 8 + 4] = *(float4*)&cv[4];
      *(ushort4*)&h_out[chunk * 8 + 0] = *(ushort4*)&hv[0];
      *(ushort4*)&h_out[chunk * 8 + 4] = *(ushort4*)&hv[4];
      s0 += __shfl_xor(s0, 16); s1 += __shfl_xor(s1, 16); s2 += __shfl_xor(s2, 16);
      s0 += __shfl_xor(s0, 32); s1 += __shfl_xor(s1, 32); s2 += __shfl_xor(s2, 32);
      if (quad == 0) {
        atomicAdd(&coords[((size_t)bg * T_DIM + trow) * 2 + 0], s0);
        atomicAdd(&coords[((size_t)bg * T_DIM + trow) * 2 + 1], s1);
        atomicAdd(&stops[(size_t)bg * T_DIM + trow], s2);
      }
    }
  }
}

extern "C" void kernel_launch(void* const* d_in, const int* in_sizes, int n_in,
                              void* d_out, int out_size, void* d_ws, size_t ws_size,
                              hipStream_t stream) {
  const float* embedding = (const float*)d_in[0];
  const float* W_embed   = (const float*)d_in[2];
  const float* b_embed   = (const float*)d_in[3];
  const float* W_ih      = (const float*)d_in[4];
  const float* b_ih      = (const float*)d_in[5];
  const float* W_hh      = (const float*)d_in[6];
  const float* b_hh      = (const float*)d_in[7];
  const float* W_out     = (const float*)d_in[8];
  const float* b_out     = (const float*)d_in[9];
  const float* W_stop    = (const float*)d_in[10];
  const float* b_stop    = (const float*)d_in[11];

  float* coords = (float*)d_out;
  float* stops  = (float*)d_out + (size_t)B_DIM * T_DIM * 2;

  char* ws = (char*)d_ws;
  u16* W_z     = (u16*)ws;   ws += (size_t)G4H * H_DIM * 2;    // 32 MB
  u16* W_emb_b = (u16*)ws;   ws += (size_t)H_DIM * E_DIM * 2;  // 8 MB
  u16* emb_b   = (u16*)ws;   ws += (size_t)B_DIM * E_DIM * 2;  // 2 MB
  float* h0pre = (float*)ws; ws += (size_t)B_DIM * H_DIM * 4;  // 4 MB
  float* epi   = (float*)ws; ws += (size_t)G4H * 4 * 4;        // 128 KB
  float* cbuf  = (float*)ws; ws += (size_t)B_DIM * H_DIM * 4;  // 4 MB
  u16* hbuf0   = (u16*)ws;   ws += (size_t)B_DIM * H_DIM * 2;  // 2 MB
  u16* hbuf1   = (u16*)ws;   ws += (size_t)B_DIM * H_DIM * 2;  // 2 MB
  float* xcorr = (float*)ws; ws += (size_t)B_DIM * 2 * 4;
  float* xzero = (float*)ws; ws += (size_t)B_DIM * 2 * 4;

  convert_bf16<<<(B_DIM * E_DIM / 4 + 255) / 256, 256, 0, stream>>>(embedding, emb_b, B_DIM * E_DIM / 4);
  convert_bf16<<<(H_DIM * E_DIM / 4 + 255) / 256, 256, 0, stream>>>(W_embed, W_emb_b, H_DIM * E_DIM / 4);
  build_weff<<<(G4H * H_DIM / 8) / 256, 256, 0, stream>>>(W_hh, W_ih, W_out, W_z);
  build_epi<<<G4H / 256, 256, 0, stream>>>(b_ih, b_hh, W_ih, b_out, epi);
  init_out<<<(B_DIM * T_DIM) / 256, 256, 0, stream>>>(b_out, b_stop, coords, stops);

  gemm_bt<<<dim3(H_DIM / BN, B_DIM / BM), 256, 0, stream>>>(emb_b, W_emb_b, h0pre,
                                                            B_DIM, H_DIM, E_DIM);
  init_state<<<(B_DIM * H_DIM) / 256, 256, 0, stream>>>(h0pre, b_embed, hbuf0, cbuf, xzero);
  calc_xcorr<<<B_DIM, 64, 0, stream>>>(h0pre, b_embed, W_out, b_out, xcorr);

  for (int t = 0; t < T_DIM; ++t) {
    u16* h_in  = (t & 1) ? hbuf1 : hbuf0;
    u16* h_out = (t & 1) ? hbuf0 : hbuf1;
    const float* xv = (t == 0) ? xcorr : xzero;
    gemm_lstm<<<256, 512, 0, stream>>>(h_in, W_z, epi, xv, cbuf, h_out,
                                       W_out, W_stop, coords, stops, t);
  }
  finalize_stops<<<(B_DIM * T_DIM) / 256, 256, 0, stream>>>(stops);
}